// Round 8
// baseline (130.414 us; speedup 1.0000x reference)
//
#include <hip/hip_runtime.h>
#include <math.h>

// SinkhornM round 9 RESUBMIT (round 7 was an infra failure: container died,
// no kernel verdict). Identical source to the round-9 proposal.
//
// R8 math (bit-identical op order) with ROLLED loops to shrink code
// footprint ~25KB -> ~8KB (I$-streaming stall theory).
//  - MLP: 4 fused L1->L2 strips of 8 hidden units, rolled (#pragma unroll 1);
//    inner loops fully unrolled so all reg arrays are statically indexed
//    (dynamic-index -> scratch, rule learned R4/R6).
//  - L3 unrolled (needs static h2 extraction).
//  - Sinkhorn: rolled 9 iters + explicit final half-step (same op sequence
//    as R8's `if(it<9)` unrolled form).
//  - Weights via s_load (uniform strip offsets); R=2; interleaved tail.
// Tripwires: WRITE_SIZE ~69632 KB (no scratch); absmax must stay 0.00390625
// (accumulation order unchanged -> bit-identical).

#define QLOW  0.02f
#define QSPAN 0.96f
#define L2E   1.44269504088896f

constexpr int R = 2;

typedef __attribute__((ext_vector_type(2))) float f32x2;

__device__ __forceinline__ float frcp(float x) { return __builtin_amdgcn_rcpf(x); }
__device__ __forceinline__ f32x2 pfma(f32x2 a, f32x2 b, f32x2 c) {
    return __builtin_elementwise_fma(a, b, c);
}

__global__ __launch_bounds__(256) void sinkhorn_fused(
    const float* __restrict__ margins,
    const float* __restrict__ W1, const float* __restrict__ b1,
    const float* __restrict__ W2, const float* __restrict__ b2,
    const float* __restrict__ W3, const float* __restrict__ b3,
    float* __restrict__ out, int n)
{
    const int tid  = blockIdx.x * blockDim.x + threadIdx.x;
    const int lane = tid & 63;
    const int base = (tid >> 6) * (64 * R) + lane;  // rows base, base+64

    const float4* __restrict__ m4 = (const float4*)margins;

    float m[R][8];
#pragma unroll
    for (int r = 0; r < R; ++r) {
        const int row = base + 64 * r;
        const float4 a0 = m4[row * 2 + 0];
        const float4 a1 = m4[row * 2 + 1];
        m[r][0] = a0.x; m[r][1] = a0.y; m[r][2] = a0.z; m[r][3] = a0.w;
        m[r][4] = a1.x; m[r][5] = a1.y; m[r][6] = a1.z; m[r][7] = a1.w;
    }

    const f32x2* __restrict__ W1v = (const f32x2*)W1;  // (8,32) -> [k][16 pairs]
    const f32x2* __restrict__ W2v = (const f32x2*)W2;  // (32,16) -> [k][8 pairs]
    const f32x2* __restrict__ b1v = (const f32x2*)b1;
    const f32x2* __restrict__ b2v = (const f32x2*)b2;

    const f32x2 zero2 = {0.0f, 0.0f};

    // ---- h2 accumulators, bias-initialized (same order as R8) ----
    f32x2 h2[R][8];
#pragma unroll
    for (int j = 0; j < 8; ++j) {
        const f32x2 bb = b2v[j];
#pragma unroll
        for (int r = 0; r < R; ++r) h2[r][j] = bb;
    }

    // ---- fused L1->L2 in 4 rolled strips of 8 hidden units ----
#pragma unroll 1
    for (int s = 0; s < 4; ++s) {
        // L1 strip: units 8s..8s+7 = 4 f32x2 pairs per row
        f32x2 hs[R][4];
#pragma unroll
        for (int jp = 0; jp < 4; ++jp) {
            const f32x2 bb = b1v[s * 4 + jp];
#pragma unroll
            for (int r = 0; r < R; ++r) hs[r][jp] = bb;
        }
#pragma unroll
        for (int k = 0; k < 8; ++k) {
            f32x2 mk[R];
#pragma unroll
            for (int r = 0; r < R; ++r) { mk[r].x = m[r][k]; mk[r].y = m[r][k]; }
#pragma unroll
            for (int jp = 0; jp < 4; ++jp) {
                const f32x2 w = W1v[k * 16 + s * 4 + jp];
#pragma unroll
                for (int r = 0; r < R; ++r) hs[r][jp] = pfma(mk[r], w, hs[r][jp]);
            }
        }
#pragma unroll
        for (int jp = 0; jp < 4; ++jp)
#pragma unroll
            for (int r = 0; r < R; ++r)
                hs[r][jp] = __builtin_elementwise_max(hs[r][jp], zero2);

        // L2 strip: consume the 8 units immediately (k ascending globally)
#pragma unroll
        for (int kk = 0; kk < 8; ++kk) {
            f32x2 hk[R];
#pragma unroll
            for (int r = 0; r < R; ++r) {
                const float sc = (kk & 1) ? hs[r][kk >> 1].y : hs[r][kk >> 1].x;
                hk[r].x = sc; hk[r].y = sc;
            }
#pragma unroll
            for (int j = 0; j < 8; ++j) {
                const f32x2 w = W2v[(s * 8 + kk) * 8 + j];
#pragma unroll
                for (int r = 0; r < R; ++r) h2[r][j] = pfma(hk[r], w, h2[r][j]);
            }
        }
    }
#pragma unroll
    for (int j = 0; j < 8; ++j)
#pragma unroll
        for (int r = 0; r < R; ++r)
            h2[r][j] = __builtin_elementwise_max(h2[r][j], zero2);

    // ---- layer 3: p = h2 @ W3 + b3, unrolled (static h2 extraction) ----
    f32x2 p01[R], p23[R], p45[R], p67[R];
    float p8[R];
    {
        const f32x2 b01 = {b3[0], b3[1]};
        const f32x2 b23 = {b3[2], b3[3]};
        const f32x2 b45 = {b3[4], b3[5]};
        const f32x2 b67 = {b3[6], b3[7]};
        const float b8  = b3[8];
#pragma unroll
        for (int r = 0; r < R; ++r) {
            p01[r] = b01; p23[r] = b23; p45[r] = b45; p67[r] = b67; p8[r] = b8;
        }
    }
#pragma unroll
    for (int k = 0; k < 16; ++k) {
        const f32x2 w01 = {W3[k * 9 + 0], W3[k * 9 + 1]};
        const f32x2 w23 = {W3[k * 9 + 2], W3[k * 9 + 3]};
        const f32x2 w45 = {W3[k * 9 + 4], W3[k * 9 + 5]};
        const f32x2 w67 = {W3[k * 9 + 6], W3[k * 9 + 7]};
        const float w8  = W3[k * 9 + 8];
#pragma unroll
        for (int r = 0; r < R; ++r) {
            const float sc = (k & 1) ? h2[r][k >> 1].y : h2[r][k >> 1].x;
            f32x2 hb; hb.x = sc; hb.y = sc;
            p01[r] = pfma(hb, w01, p01[r]);
            p23[r] = pfma(hb, w23, p23[r]);
            p45[r] = pfma(hb, w45, p45[r]);
            p67[r] = pfma(hb, w67, p67[r]);
            p8[r]  = fmaf(sc, w8, p8[r]);
        }
    }

    // ---- per-row tail state (both rows live; minimal set; same as R8) ----
    float aa[R][9];
    float rm[R][3], cm[R][3];
    float t0_[R], t1_[R], t2_[R];
    float Vv[R];

#pragma unroll
    for (int r = 0; r < R; ++r) {
        const float l0 = p01[r].x * L2E, l1 = p01[r].y * L2E;
        const float l2 = p23[r].x * L2E, l3 = p23[r].y * L2E;

        const float a00 = exp2f(l0), a01 = exp2f(l1);
        const float a10 = exp2f(l2), a11 = exp2f(l3);
        const float h01 = (l0 + l1) * 0.5f, h23 = (l2 + l3) * 0.5f;
        const float a02 = exp2f(h01);
        const float a12 = exp2f(h23);
        const float a20 = exp2f((l0 + l2) * 0.5f);
        const float a21 = exp2f((l1 + l3) * 0.5f);
        const float a22 = exp2f((h01 + h23) * 0.5f);
        aa[r][0] = a00; aa[r][1] = a01; aa[r][2] = a02;
        aa[r][3] = a10; aa[r][4] = a11; aa[r][5] = a12;
        aa[r][6] = a20; aa[r][7] = a21; aa[r][8] = a22;

        const float s4 = fmaf(QSPAN, frcp(1.0f + exp2f(-L2E * p45[r].x)), QLOW);
        const float s5 = fmaf(QSPAN, frcp(1.0f + exp2f(-L2E * p45[r].y)), QLOW);
        const float s6 = fmaf(QSPAN, frcp(1.0f + exp2f(-L2E * p67[r].x)), QLOW);
        const float s7 = fmaf(QSPAN, frcp(1.0f + exp2f(-L2E * p67[r].y)), QLOW);

        rm[r][0] = m[r][0] * s4; rm[r][1] = m[r][1] * s5; rm[r][2] = m[r][2];
        cm[r][0] = m[r][3] * s6; cm[r][1] = m[r][4] * s7; cm[r][2] = m[r][5];

        t0_[r] = (a00 + a01) + a02;   // A @ v with v = 1
        t1_[r] = (a10 + a11) + a12;
        t2_[r] = (a20 + a21) + a22;

        Vv[r] = exp2f(p8[r] * L2E);
    }

    // ---- interleaved Sinkhorn, ROLLED: 9 full iters + final half-step ----
    float zp0[R], zp1[R], zp2[R], wp0[R], wp1[R], wp2[R];
#pragma unroll 1
    for (int it = 0; it < 9; ++it) {
#pragma unroll
        for (int r = 0; r < R; ++r) {
            zp0[r] = rm[r][0] * frcp(t0_[r]);
            zp1[r] = rm[r][1] * frcp(t1_[r]);
            zp2[r] = rm[r][2] * frcp(t2_[r]);
        }
#pragma unroll
        for (int r = 0; r < R; ++r) {
            const float q0 = fmaf(aa[r][6], zp2[r], fmaf(aa[r][3], zp1[r], aa[r][0] * zp0[r]));
            const float q1 = fmaf(aa[r][7], zp2[r], fmaf(aa[r][4], zp1[r], aa[r][1] * zp0[r]));
            const float q2 = fmaf(aa[r][8], zp2[r], fmaf(aa[r][5], zp1[r], aa[r][2] * zp0[r]));
            wp0[r] = cm[r][0] * frcp(q0);
            wp1[r] = cm[r][1] * frcp(q1);
            wp2[r] = cm[r][2] * frcp(q2);
        }
#pragma unroll
        for (int r = 0; r < R; ++r) {
            t0_[r] = fmaf(aa[r][2], wp2[r], fmaf(aa[r][1], wp1[r], aa[r][0] * wp0[r]));
            t1_[r] = fmaf(aa[r][5], wp2[r], fmaf(aa[r][4], wp1[r], aa[r][3] * wp0[r]));
            t2_[r] = fmaf(aa[r][8], wp2[r], fmaf(aa[r][7], wp1[r], aa[r][6] * wp0[r]));
        }
    }
    // final half-step (iteration 10, no t-update) -- same ops as R8's it==9
#pragma unroll
    for (int r = 0; r < R; ++r) {
        zp0[r] = rm[r][0] * frcp(t0_[r]);
        zp1[r] = rm[r][1] * frcp(t1_[r]);
        zp2[r] = rm[r][2] * frcp(t2_[r]);
    }
#pragma unroll
    for (int r = 0; r < R; ++r) {
        const float q0 = fmaf(aa[r][6], zp2[r], fmaf(aa[r][3], zp1[r], aa[r][0] * zp0[r]));
        const float q1 = fmaf(aa[r][7], zp2[r], fmaf(aa[r][4], zp1[r], aa[r][1] * zp0[r]));
        const float q2 = fmaf(aa[r][8], zp2[r], fmaf(aa[r][5], zp1[r], aa[r][2] * zp0[r]));
        wp0[r] = cm[r][0] * frcp(q0);
        wp1[r] = cm[r][1] * frcp(q1);
        wp2[r] = cm[r][2] * frcp(q2);
    }

    float4* __restrict__ o4 = (float4*)out;
    float* __restrict__ oV = out + (size_t)n * 16;

#pragma unroll
    for (int r = 0; r < R; ++r) {
        const int row = base + 64 * r;
        const float u0 = zp0[r], u1 = zp1[r], u2 = zp2[r];
        const float v0 = wp0[r], v1 = wp1[r], v2 = wp2[r];

        const float A0f = u0 * aa[r][0] * v0, A1f = u0 * aa[r][1] * v1, A2f = u0 * aa[r][2] * v2;
        const float A3f = u1 * aa[r][3] * v0, A4f = u1 * aa[r][4] * v1, A5f = u1 * aa[r][5] * v2;
        const float A6f = u2 * aa[r][6] * v0, A7f = u2 * aa[r][7] * v1, A8f = u2 * aa[r][8] * v2;

        const float um0 = m[r][0] - rm[r][0];
        const float um1 = m[r][1] - rm[r][1];
        const float uf0 = m[r][3] - cm[r][0];
        const float uf1 = m[r][4] - cm[r][1];

        o4[row * 4 + 0] = make_float4(A0f, A1f, A2f, um0);
        o4[row * 4 + 1] = make_float4(A3f, A4f, A5f, um1);
        o4[row * 4 + 2] = make_float4(A6f, A7f, A8f, 0.0f);
        o4[row * 4 + 3] = make_float4(uf0, uf1, 0.0f, 0.0f);
        oV[row] = Vv[r];
    }
}

extern "C" void kernel_launch(void* const* d_in, const int* in_sizes, int n_in,
                              void* d_out, int out_size, void* d_ws, size_t ws_size,
                              hipStream_t stream) {
    const float* margins = (const float*)d_in[0];
    const float* W1 = (const float*)d_in[1];
    const float* b1 = (const float*)d_in[2];
    const float* W2 = (const float*)d_in[3];
    const float* b2 = (const float*)d_in[4];
    const float* W3 = (const float*)d_in[5];
    const float* b3 = (const float*)d_in[6];

    const int n = in_sizes[0] / 8;       // 1,048,576 rows
    const int threads = n / R;
    dim3 block(256), grid(threads / 256);

    sinkhorn_fused<<<grid, block, 0, stream>>>(margins, W1, b1, W2, b2, W3, b3,
                                               (float*)d_out, n);
}

// Round 9
// 129.839 us; speedup vs baseline: 1.0044x; 1.0044x over previous
//
#include <hip/hip_runtime.h>
#include <math.h>

// SinkhornM round 10: R8's exact math, R=1 (one row/thread), s_load weights.
//  - Isolates the R=1 variable (R7 confounded it with LDS delivery).
//  - 16384 waves = 2 per wave-slot: surplus waves to hide the serial
//    rcp/exp chains that R=2's single-pass launch left exposed.
//  - launch_bounds(256,8): pin VGPR <= 64 (occupancy halves above 64, m69).
//  - Tail: folded Sinkhorn, on-the-fly rm/cm fold (R8-verified op order).
// Tripwires: WRITE_SIZE ~69632 KB (no spill); absmax 0.00390625.

#define QLOW  0.02f
#define QSPAN 0.96f
#define L2E   1.44269504088896f

typedef __attribute__((ext_vector_type(2))) float f32x2;

__device__ __forceinline__ float frcp(float x) { return __builtin_amdgcn_rcpf(x); }
__device__ __forceinline__ f32x2 pfma(f32x2 a, f32x2 b, f32x2 c) {
    return __builtin_elementwise_fma(a, b, c);
}

__global__ __launch_bounds__(256, 8) void sinkhorn_fused(
    const float* __restrict__ margins,
    const float* __restrict__ W1, const float* __restrict__ b1,
    const float* __restrict__ W2, const float* __restrict__ b2,
    const float* __restrict__ W3, const float* __restrict__ b3,
    float* __restrict__ out, int n)
{
    const int row = blockIdx.x * blockDim.x + threadIdx.x;  // 1 row per thread

    const float4* __restrict__ m4 = (const float4*)margins;
    const float4 a0q = m4[row * 2 + 0];
    const float4 a1q = m4[row * 2 + 1];
    float m[8];
    m[0] = a0q.x; m[1] = a0q.y; m[2] = a0q.z; m[3] = a0q.w;
    m[4] = a1q.x; m[5] = a1q.y; m[6] = a1q.z; m[7] = a1q.w;

    const f32x2* __restrict__ W1v = (const f32x2*)W1;  // (8,32) -> [k][16 pairs]
    const f32x2* __restrict__ W2v = (const f32x2*)W2;  // (32,16) -> [k][8 pairs]
    const f32x2* __restrict__ b1v = (const f32x2*)b1;
    const f32x2* __restrict__ b2v = (const f32x2*)b2;

    const f32x2 zero2 = {0.0f, 0.0f};

    // ---- layer 1: h1 = relu(m @ W1 + b1), 32 wide = 16 pairs ----
    f32x2 h1[16];
#pragma unroll
    for (int j = 0; j < 16; ++j) h1[j] = b1v[j];
#pragma unroll
    for (int k = 0; k < 8; ++k) {
        f32x2 mk; mk.x = m[k]; mk.y = m[k];
#pragma unroll
        for (int j = 0; j < 16; ++j)
            h1[j] = pfma(mk, W1v[k * 16 + j], h1[j]);
    }
#pragma unroll
    for (int j = 0; j < 16; ++j) h1[j] = __builtin_elementwise_max(h1[j], zero2);

    // ---- layer 2: h2 = relu(h1 @ W2 + b2), 16 wide = 8 pairs ----
    f32x2 h2[8];
#pragma unroll
    for (int j = 0; j < 8; ++j) h2[j] = b2v[j];
#pragma unroll
    for (int k = 0; k < 32; ++k) {
        const float s = (k & 1) ? h1[k >> 1].y : h1[k >> 1].x;
        f32x2 hk; hk.x = s; hk.y = s;
#pragma unroll
        for (int j = 0; j < 8; ++j)
            h2[j] = pfma(hk, W2v[k * 8 + j], h2[j]);
    }
#pragma unroll
    for (int j = 0; j < 8; ++j) h2[j] = __builtin_elementwise_max(h2[j], zero2);

    // ---- layer 3: p = h2 @ W3 + b3, 9 wide = 4 pairs + 1 scalar ----
    f32x2 p01 = {b3[0], b3[1]};
    f32x2 p23 = {b3[2], b3[3]};
    f32x2 p45 = {b3[4], b3[5]};
    f32x2 p67 = {b3[6], b3[7]};
    float p8 = b3[8];
#pragma unroll
    for (int k = 0; k < 16; ++k) {
        const f32x2 w01 = {W3[k * 9 + 0], W3[k * 9 + 1]};
        const f32x2 w23 = {W3[k * 9 + 2], W3[k * 9 + 3]};
        const f32x2 w45 = {W3[k * 9 + 4], W3[k * 9 + 5]};
        const f32x2 w67 = {W3[k * 9 + 6], W3[k * 9 + 7]};
        const float w8  = W3[k * 9 + 8];
        const float s = (k & 1) ? h2[k >> 1].y : h2[k >> 1].x;
        f32x2 hb; hb.x = s; hb.y = s;
        p01 = pfma(hb, w01, p01);
        p23 = pfma(hb, w23, p23);
        p45 = pfma(hb, w45, p45);
        p67 = pfma(hb, w67, p67);
        p8  = fmaf(s, w8, p8);
    }

    // ---- tau in exp2/log2 space ----
    const float l0 = p01.x * L2E, l1 = p01.y * L2E;
    const float l2 = p23.x * L2E, l3 = p23.y * L2E;

    const float a00 = exp2f(l0), a01 = exp2f(l1);
    const float a10 = exp2f(l2), a11 = exp2f(l3);
    const float h01 = (l0 + l1) * 0.5f, h23 = (l2 + l3) * 0.5f;
    const float a02 = exp2f(h01);
    const float a12 = exp2f(h23);
    const float a20 = exp2f((l0 + l2) * 0.5f);
    const float a21 = exp2f((l1 + l3) * 0.5f);
    const float a22 = exp2f((h01 + h23) * 0.5f);

    const float s4 = fmaf(QSPAN, frcp(1.0f + exp2f(-L2E * p45.x)), QLOW);
    const float s5 = fmaf(QSPAN, frcp(1.0f + exp2f(-L2E * p45.y)), QLOW);
    const float s6 = fmaf(QSPAN, frcp(1.0f + exp2f(-L2E * p67.x)), QLOW);
    const float s7 = fmaf(QSPAN, frcp(1.0f + exp2f(-L2E * p67.y)), QLOW);

    const float rm0 = m[0] * s4, rm1 = m[1] * s5, rm2 = m[2];
    const float cm0 = m[3] * s6, cm1 = m[4] * s7, cm2 = m[5];

    float t0 = (a00 + a01) + a02;   // A @ v with v = 1
    float t1 = (a10 + a11) + a12;
    float t2 = (a20 + a21) + a22;

    // ---- Sinkhorn: on-the-fly folded (zp==u, wp==v; R8-verified) ----
    float zp0, zp1, zp2, wp0, wp1, wp2;
#pragma unroll
    for (int it = 0; it < 10; ++it) {
        zp0 = rm0 * frcp(t0);
        zp1 = rm1 * frcp(t1);
        zp2 = rm2 * frcp(t2);
        const float q0 = fmaf(a20, zp2, fmaf(a10, zp1, a00 * zp0));
        const float q1 = fmaf(a21, zp2, fmaf(a11, zp1, a01 * zp0));
        const float q2 = fmaf(a22, zp2, fmaf(a12, zp1, a02 * zp0));
        wp0 = cm0 * frcp(q0);
        wp1 = cm1 * frcp(q1);
        wp2 = cm2 * frcp(q2);
        if (it < 9) {
            t0 = fmaf(a02, wp2, fmaf(a01, wp1, a00 * wp0));
            t1 = fmaf(a12, wp2, fmaf(a11, wp1, a10 * wp0));
            t2 = fmaf(a22, wp2, fmaf(a21, wp1, a20 * wp0));
        }
    }

    const float A0f = zp0 * a00 * wp0, A1f = zp0 * a01 * wp1, A2f = zp0 * a02 * wp2;
    const float A3f = zp1 * a10 * wp0, A4f = zp1 * a11 * wp1, A5f = zp1 * a12 * wp2;
    const float A6f = zp2 * a20 * wp0, A7f = zp2 * a21 * wp1, A8f = zp2 * a22 * wp2;

    const float um0 = m[0] - rm0;
    const float um1 = m[1] - rm1;
    const float uf0 = m[3] - cm0;
    const float uf1 = m[4] - cm1;

    float4* __restrict__ o4 = (float4*)out;
    float* __restrict__ oV = out + (size_t)n * 16;

    o4[row * 4 + 0] = make_float4(A0f, A1f, A2f, um0);
    o4[row * 4 + 1] = make_float4(A3f, A4f, A5f, um1);
    o4[row * 4 + 2] = make_float4(A6f, A7f, A8f, 0.0f);
    o4[row * 4 + 3] = make_float4(uf0, uf1, 0.0f, 0.0f);
    oV[row] = exp2f(p8 * L2E);
}

extern "C" void kernel_launch(void* const* d_in, const int* in_sizes, int n_in,
                              void* d_out, int out_size, void* d_ws, size_t ws_size,
                              hipStream_t stream) {
    const float* margins = (const float*)d_in[0];
    const float* W1 = (const float*)d_in[1];
    const float* b1 = (const float*)d_in[2];
    const float* W2 = (const float*)d_in[3];
    const float* b2 = (const float*)d_in[4];
    const float* W3 = (const float*)d_in[5];
    const float* b3 = (const float*)d_in[6];

    const int n = in_sizes[0] / 8;       // 1,048,576 rows
    dim3 block(256), grid(n / 256);      // 1 row per thread -> 4096 blocks

    sinkhorn_fused<<<grid, block, 0, stream>>>(margins, W1, b1, W2, b2, W3, b3,
                                               (float*)d_out, n);
}